// Round 7
// baseline (1171.243 us; speedup 1.0000x reference)
//
#include <hip/hip_runtime.h>
#include <hip/hip_bf16.h>
#include <math.h>

// B=2, N=4096, C=1024, HEADS=16, DH=64, BUCKET=64, N_HASHES=4, n_buckets=64
// BH=32, T=4096, 256 bins (r*64+b), 256 chunks of 64 slots per bh.
//
// NUMERICS CONTRACT: the discrete path — qk projection and bucket rotation —
// must be an ascending-k fp32 FMA chain per output element (replicates the
// numpy fp32 reference's argmax decisions). proj2/sgemm_out preserve that
// chain bit-for-bit: k = 0..1023 strictly ascending into ONE fp32 accumulator
// per output element (BK only regroups the memory staging, not the chain).
// bucket32 / countsort / attn / combine byte-identical to round 6.
//
// ROUND 7 (post-mortem r6: proj2 420us @ VALUBusy 68% — stall-bound on the
// per-K-step barrier+vmcnt drain, not issue-bound):
//  * proj2/sgemm_out: BK=8 -> BK=16. Half the barriers (64 K-steps), half
//    the vmcnt drains, 2x FMA cover (2048 cyc) per staging batch. LDS 32KB
//    (still 4 blocks/CU). __launch_bounds__(256,4) pins VGPR<=128 so the
//    extra staging registers can't drop occupancy (m69: waves step at 128).

// ---------------------------------------------------------------------------
// Shared inner loop: 128x128 tile, BK=16, 256 threads, 8x8 micro-tile with
// split rows/cols (a@tx*4 & 64+tx*4, b@ty*4 & 64+ty*4): all LDS reads
// <=2-way bank aliasing (free). kk ascending 0..15 -> k ascending globally.
// ---------------------------------------------------------------------------
#define SG_COMPUTE(BUF)                                                      \
    {                                                                        \
        _Pragma("unroll")                                                    \
        for (int kk = 0; kk < 16; ++kk) {                                    \
            float a[8], b[8];                                                \
            *(float4*)&a[0] = *(const float4*)&As[BUF][kk][tx * 4];          \
            *(float4*)&a[4] = *(const float4*)&As[BUF][kk][64 + tx * 4];     \
            *(float4*)&b[0] = *(const float4*)&Bs[BUF][kk][ty * 4];          \
            *(float4*)&b[4] = *(const float4*)&Bs[BUF][kk][64 + ty * 4];     \
            _Pragma("unroll")                                                \
            for (int i = 0; i < 8; ++i)                                      \
                _Pragma("unroll")                                            \
                for (int j = 0; j < 8; ++j)                                  \
                    acc[i][j] = fmaf(a[i], b[j], acc[i][j]);                 \
        }                                                                    \
    }

// stage one BK=16 tile: each thread wrote k-cols lk..lk+3 and lk+8..lk+11
// of its row lr (av0/bv0 = k lk.., av1/bv1 = k lk+8..).
#define SG_STAGE(BUF)                                                        \
    {                                                                        \
        As[BUF][lk + 0][lr] = av0.x; As[BUF][lk + 1][lr] = av0.y;            \
        As[BUF][lk + 2][lr] = av0.z; As[BUF][lk + 3][lr] = av0.w;            \
        As[BUF][lk + 8][lr] = av1.x; As[BUF][lk + 9][lr] = av1.y;            \
        As[BUF][lk + 10][lr] = av1.z; As[BUF][lk + 11][lr] = av1.w;          \
        Bs[BUF][lk + 0][lr] = bv0.x; Bs[BUF][lk + 1][lr] = bv0.y;            \
        Bs[BUF][lk + 2][lr] = bv0.z; Bs[BUF][lk + 3][lr] = bv0.w;            \
        Bs[BUF][lk + 8][lr] = bv1.x; Bs[BUF][lk + 9][lr] = bv1.y;            \
        Bs[BUF][lk + 10][lr] = bv1.z; Bs[BUF][lk + 11][lr] = bv1.w;          \
    }

#define SG_LOAD(IT)                                                          \
    {                                                                        \
        av0 = *(const float4*)&pA[(IT) * 16];                                \
        av1 = *(const float4*)&pA[(IT) * 16 + 8];                            \
        bv0 = *(const float4*)&pB[(IT) * 16];                                \
        bv1 = *(const float4*)&pB[(IT) * 16 + 8];                            \
    }

// ---------------------------------------------------------------------------
// Fused projection: C[m, 0:2048] = x . [Wqk; Wv]^T, head-layout outputs.
// Grid 1024: swz=(id&7)*128+(id>>3); tm=swz>>4 (64 m-tiles), tn=swz&15.
// tn<8 -> Wqk -> outQK; tn>=8 -> Wv -> outV.
// ---------------------------------------------------------------------------
__global__ __launch_bounds__(256, 4) void proj2(const float* __restrict__ A,
                                                const float* __restrict__ Wqk,
                                                const float* __restrict__ Wv,
                                                float* __restrict__ outQK,
                                                float* __restrict__ outV) {
    __shared__ float As[2][16][128];
    __shared__ float Bs[2][16][128];
    int tid = threadIdx.x;
    int tx = tid & 15, ty = tid >> 4;
    int id = blockIdx.x;                      // 0..1023
    int swz = (id & 7) * 128 + (id >> 3);
    int tm = swz >> 4;                        // 0..63
    int tn = swz & 15;                        // 0..15
    int m0 = tm * 128;
    const float* Wsel = (tn < 8) ? Wqk : Wv;
    float* dst = (tn < 8) ? outQK : outV;
    int nsel = (tn & 7) * 128;                // col base within selected matrix
    int lr = tid >> 1;                        // 0..127
    int lk = (tid & 1) * 4;                   // 0 or 4
    const float* pA = &A[(size_t)(m0 + lr) * 1024 + lk];
    const float* pB = &Wsel[(size_t)(nsel + lr) * 1024 + lk];
    float acc[8][8];
#pragma unroll
    for (int i = 0; i < 8; ++i)
#pragma unroll
        for (int j = 0; j < 8; ++j) acc[i][j] = 0.f;

    float4 av0, av1, bv0, bv1;
    SG_LOAD(0)
    SG_STAGE(0)
    __syncthreads();

    // 63 pipelined K-steps (BK=16); tile it lives in buffer it&1. Write of
    // buf[nxt] in iter it is safe: buf[nxt] was last READ in iter it-1,
    // sealed by iter it-1's barrier.
    for (int it = 0; it < 63; ++it) {
        int cur = it & 1;
        int nxt = cur ^ 1;
        SG_LOAD(it + 1)
        SG_COMPUTE(cur)
        SG_STAGE(nxt)
        __syncthreads();
    }
    // epilogue: tile 63 is in buffer 1; no barrier needed after.
    SG_COMPUTE(1)

    // epilogue: col group 0 -> head h0 = nsel>>6, d = ty*4..+3;
    //           col group 1 -> head h0+1, same d. float4 stores.
    int h0 = nsel >> 6;
#pragma unroll
    for (int i = 0; i < 8; ++i) {
        int m = m0 + ((i < 4) ? (tx * 4 + i) : (64 + tx * 4 + (i - 4)));
        int bb = m >> 12, t = m & 4095;
        float4 o0, o1;
        o0.x = acc[i][0]; o0.y = acc[i][1]; o0.z = acc[i][2]; o0.w = acc[i][3];
        o1.x = acc[i][4]; o1.y = acc[i][5]; o1.z = acc[i][6]; o1.w = acc[i][7];
        *(float4*)&dst[(((size_t)(bb * 16 + h0)) * 4096 + t) * 64 + ty * 4] = o0;
        *(float4*)&dst[(((size_t)(bb * 16 + h0 + 1)) * 4096 + t) * 64 + ty * 4] = o1;
    }
}

// ---------------------------------------------------------------------------
// Output GEMM: out[m][n] = o_bt . Wout^T + bout, row-major. Grid 512:
// swz=(id&7)*64+(id>>3); tm=swz>>3 (64 m-tiles), tn=swz&7 (8 n-tiles).
// ---------------------------------------------------------------------------
__global__ __launch_bounds__(256, 4) void sgemm_out(const float* __restrict__ A,
                                                    const float* __restrict__ W,
                                                    float* __restrict__ out,
                                                    const float* __restrict__ bias) {
    __shared__ float As[2][16][128];
    __shared__ float Bs[2][16][128];
    int tid = threadIdx.x;
    int tx = tid & 15, ty = tid >> 4;
    int id = blockIdx.x;                      // 0..511
    int swz = (id & 7) * 64 + (id >> 3);
    int tm = swz >> 3;                        // 0..63
    int tn = swz & 7;                         // 0..7
    int m0 = tm * 128, n0 = tn * 128;
    int lr = tid >> 1;
    int lk = (tid & 1) * 4;
    const float* pA = &A[(size_t)(m0 + lr) * 1024 + lk];
    const float* pB = &W[(size_t)(n0 + lr) * 1024 + lk];
    float acc[8][8];
#pragma unroll
    for (int i = 0; i < 8; ++i)
#pragma unroll
        for (int j = 0; j < 8; ++j) acc[i][j] = 0.f;

    float4 av0, av1, bv0, bv1;
    SG_LOAD(0)
    SG_STAGE(0)
    __syncthreads();

    for (int it = 0; it < 63; ++it) {
        int cur = it & 1;
        int nxt = cur ^ 1;
        SG_LOAD(it + 1)
        SG_COMPUTE(cur)
        SG_STAGE(nxt)
        __syncthreads();
    }
    SG_COMPUTE(1)

    float4 bias0 = *(const float4*)&bias[n0 + ty * 4];
    float4 bias1 = *(const float4*)&bias[n0 + 64 + ty * 4];
#pragma unroll
    for (int i = 0; i < 8; ++i) {
        int m = m0 + ((i < 4) ? (tx * 4 + i) : (64 + tx * 4 + (i - 4)));
        float4 o0, o1;
        o0.x = acc[i][0] + bias0.x; o0.y = acc[i][1] + bias0.y;
        o0.z = acc[i][2] + bias0.z; o0.w = acc[i][3] + bias0.w;
        o1.x = acc[i][4] + bias1.x; o1.y = acc[i][5] + bias1.y;
        o1.z = acc[i][6] + bias1.z; o1.w = acc[i][7] + bias1.w;
        *(float4*)&out[(size_t)m * 1024 + n0 + ty * 4] = o0;
        *(float4*)&out[(size_t)m * 1024 + n0 + 64 + ty * 4] = o1;
    }
}
#undef SG_COMPUTE
#undef SG_STAGE
#undef SG_LOAD

// ---------------------------------------------------------------------------
// Bucketing (byte-identical to round 6).
// ---------------------------------------------------------------------------
__global__ __launch_bounds__(256) void bucket32(const float* __restrict__ qk,
                                                const float* __restrict__ rot,
                                                int* __restrict__ keys) {
    int tid = threadIdx.x;
    int blk = blockIdx.x;                 // 0..2047
    int token = (blk & 15) * 256 + tid;
    int r = (blk >> 4) & 3;               // block-uniform
    int bh = blk >> 6;                    // block-uniform
    const float* q = &qk[((size_t)bh * 4096 + token) * 64];
    float racc[32];
#pragma unroll
    for (int i = 0; i < 32; ++i) racc[i] = 0.f;
    for (int f0 = 0; f0 < 64; f0 += 4) {
        float4 qv = *(const float4*)&q[f0];
        const float* rp0 = &rot[(f0 + 0) * 128 + r * 32];
        const float* rp1 = rp0 + 128;
        const float* rp2 = rp0 + 256;
        const float* rp3 = rp0 + 384;
#pragma unroll
        for (int i = 0; i < 32; ++i) racc[i] = fmaf(qv.x, rp0[i], racc[i]);
#pragma unroll
        for (int i = 0; i < 32; ++i) racc[i] = fmaf(qv.y, rp1[i], racc[i]);
#pragma unroll
        for (int i = 0; i < 32; ++i) racc[i] = fmaf(qv.z, rp2[i], racc[i]);
#pragma unroll
        for (int i = 0; i < 32; ++i) racc[i] = fmaf(qv.w, rp3[i], racc[i]);
    }
    float best = -INFINITY;
    int bi = 0;
#pragma unroll
    for (int i = 0; i < 32; ++i) { if (racc[i] > best) { best = racc[i]; bi = i; } }
#pragma unroll
    for (int i = 0; i < 32; ++i) { float x = -racc[i]; if (x > best) { best = x; bi = 32 + i; } }
    int bin = r * 64 + bi;
    keys[(size_t)bh * 16384 + r * 4096 + token] = bin * 4096 + token;
}

// ---------------------------------------------------------------------------
// Stable counting sort per (bh, r) segment (byte-identical).
// ---------------------------------------------------------------------------
#define PST 257  // u16 row stride for pre[] (odd => spreads LDS banks)

__global__ __launch_bounds__(256) void countsort_kernel(const int* __restrict__ keys,
                                                        int* __restrict__ st_sorted) {
    __shared__ unsigned short pre[64 * PST];
    __shared__ unsigned char sbin[4096];
    __shared__ unsigned short sperm[4096];
    __shared__ int qsum[64 * 4];
    __shared__ int qoff[64 * 4];
    __shared__ int binOffset[64];

    int tid = threadIdx.x;
    int bh = blockIdx.x >> 2;
    int r = blockIdx.x & 3;
    const int* kb = &keys[(((size_t)bh * 4 + r) << 12)];

    for (int u = tid; u < 64 * PST; u += 256) pre[u] = 0;
    __syncthreads();

    int base = tid << 4;
#pragma unroll
    for (int u = 0; u < 4; ++u) {
        int4 kv = *(const int4*)&kb[base + u * 4];
        int b0 = (kv.x >> 12) & 63;
        int b1 = (kv.y >> 12) & 63;
        int b2 = (kv.z >> 12) & 63;
        int b3 = (kv.w >> 12) & 63;
        sbin[base + u * 4 + 0] = (unsigned char)b0;
        sbin[base + u * 4 + 1] = (unsigned char)b1;
        sbin[base + u * 4 + 2] = (unsigned char)b2;
        sbin[base + u * 4 + 3] = (unsigned char)b3;
        pre[b0 * PST + tid]++;
        pre[b1 * PST + tid]++;
        pre[b2 * PST + tid]++;
        pre[b3 * PST + tid]++;
    }
    __syncthreads();

    int b = tid & 63, q = tid >> 6;
    {
        int run = 0;
        for (int i = 0; i < 64; ++i) run += pre[b * PST + q * 64 + i];
        qsum[b * 4 + q] = run;
    }
    __syncthreads();

    if (tid < 64) {
        int s0 = qsum[tid * 4 + 0], s1 = qsum[tid * 4 + 1];
        int s2 = qsum[tid * 4 + 2], s3 = qsum[tid * 4 + 3];
        qoff[tid * 4 + 0] = 0;
        qoff[tid * 4 + 1] = s0;
        qoff[tid * 4 + 2] = s0 + s1;
        qoff[tid * 4 + 3] = s0 + s1 + s2;
        binOffset[tid] = s0 + s1 + s2 + s3;
    }
    __syncthreads();
    if (tid == 0) {
        int running = 0;
        for (int i = 0; i < 64; ++i) {
            int t = binOffset[i];
            binOffset[i] = running;
            running += t;
        }
    }
    __syncthreads();

    {
        int run2 = qoff[b * 4 + q];
        for (int i = 0; i < 64; ++i) {
            int idx = b * PST + q * 64 + i;
            int t = pre[idx];
            pre[idx] = (unsigned short)run2;
            run2 += t;
        }
    }
    __syncthreads();

#pragma unroll
    for (int k = 0; k < 16; ++k) {
        int bin = sbin[base + k];
        int off = pre[bin * PST + tid]++;
        sperm[binOffset[bin] + off] = (unsigned short)(base + k);
    }
    __syncthreads();

    int* ob = &st_sorted[(((size_t)bh * 4 + r) << 12)];
#pragma unroll
    for (int u = 0; u < 16; ++u) ob[u * 256 + tid] = (int)sperm[u * 256 + tid];
}

// ---------------------------------------------------------------------------
// Tiled chunked attention (byte-identical to round 6).
// ---------------------------------------------------------------------------
__global__ __launch_bounds__(256) void attn_kernel(const float* __restrict__ qk,
                                                   const float* __restrict__ v,
                                                   const int* __restrict__ st_sorted,
                                                   float* __restrict__ o4,
                                                   float* __restrict__ lse4) {
    __shared__ float bufA[128 * 68];  // phase1: kqt[f][row^swz] stride 132; phase2: pT[j][i] stride 68
    __shared__ float red[64 * 17];
    __shared__ int posl[128];
    __shared__ int voff[128];         // posl*256: byte offset of V row
    __shared__ float invl[128];

    int tid = threadIdx.x;
    int bh = blockIdx.x >> 8;
    int c = blockIdx.x & 255;
    int r = c >> 6;
    int pc = (c + 255) & 255;
    const int* stb = &st_sorted[(size_t)bh * 16384];
    if (tid < 64) {
        int p = stb[c * 64 + tid];
        posl[tid] = p;
        voff[tid] = p << 8;           // *64 floats *4 bytes
    } else if (tid < 128) {
        int p = stb[pc * 64 + (tid - 64)];
        posl[tid] = p;
        voff[tid] = p << 8;
    }
    __syncthreads();

    // stage qk -> kqt transposed, XOR-swizzled: row' = row ^ (4*((f>>2)&7)).
    float* kqt = bufA;
#pragma unroll
    for (int u = 0; u < 8; ++u) {
        int flat = u * 256 + tid;              // 0..2047 float4 units
        int row = flat >> 4;
        int f4 = (flat & 15) * 4;
        size_t gbase = ((size_t)bh * 4096 + posl[row]) * 64 + f4;
        float4 qv = *(const float4*)&qk[gbase];
        int rw = row ^ ((((f4 >> 2)) & 7) << 2);
        kqt[(f4 + 0) * 132 + rw] = qv.x;
        kqt[(f4 + 1) * 132 + rw] = qv.y;
        kqt[(f4 + 2) * 132 + rw] = qv.z;
        kqt[(f4 + 3) * 132 + rw] = qv.w;
    }
    __syncthreads();

    if (tid < 128) {
        float ss = 0.f;
        for (int f = 0; f < 64; ++f) {
            int s = ((f >> 2) & 7) << 2;
            float x = kqt[f * 132 + (tid ^ s)];
            ss += x * x;
        }
        invl[tid] = 1.0f / fmaxf(sqrtf(ss), 1e-12f);
    }
    __syncthreads();

    int tx = tid & 15, ty = tid >> 4;   // rows i=tx*4..+4 (queries), cols j=ty*8..+8 (keys)
    float acc[4][8];
#pragma unroll
    for (int i = 0; i < 4; ++i)
#pragma unroll
        for (int j = 0; j < 8; ++j) acc[i][j] = 0.f;
#pragma unroll
    for (int f = 0; f < 64; ++f) {
        int s = ((f >> 2) & 7) << 2;
        float a[4], b[8];
        *(float4*)a = *(const float4*)&kqt[f * 132 + ((tx * 4) ^ s)];
        *(float4*)&b[0] = *(const float4*)&kqt[f * 132 + ((ty * 8) ^ s)];
        *(float4*)&b[4] = *(const float4*)&kqt[f * 132 + ((ty * 8 + 4) ^ s)];
#pragma unroll
        for (int i = 0; i < 4; ++i)
#pragma unroll
            for (int j = 0; j < 8; ++j) acc[i][j] = fmaf(a[i], b[j], acc[i][j]);
    }

    // scale + self-mask
    int qp[4];
#pragma unroll
    for (int ii = 0; ii < 4; ++ii) qp[ii] = posl[tx * 4 + ii];
#pragma unroll
    for (int jj = 0; jj < 8; ++jj) {
        int j = ty * 8 + jj;
        float sc = invl[j] * 0.125f;
        int kp = posl[j];
#pragma unroll
        for (int ii = 0; ii < 4; ++ii) {
            float x = acc[ii][jj] * sc;
            acc[ii][jj] = (qp[ii] == kp) ? -5e4f : x;
        }
    }

    // row max across the 16 ty-groups
#pragma unroll
    for (int ii = 0; ii < 4; ++ii) {
        float pm = acc[ii][0];
#pragma unroll
        for (int jj = 1; jj < 8; ++jj) pm = fmaxf(pm, acc[ii][jj]);
        red[(tx * 4 + ii) * 17 + ty] = pm;
    }
    __syncthreads();
    float m[4];
#pragma unroll
    for (int ii = 0; ii < 4; ++ii) {
        float mm = red[(tx * 4 + ii) * 17 + 0];
        for (int t = 1; t < 16; ++t) mm = fmaxf(mm, red[(tx * 4 + ii) * 17 + t]);
        m[ii] = mm;
    }
    __syncthreads();  // max reads done before red reuse + kqt reads done before pT overwrite

    // exp, store transposed probs as float4 (conflict-free), partial sums.
    float* pT = bufA;
    float ps[4] = {0.f, 0.f, 0.f, 0.f};
#pragma unroll
    for (int jj = 0; jj < 8; ++jj) {
        int j = ty * 8 + jj;
        float e0 = __expf(acc[0][jj] - m[0]);
        float e1 = __expf(acc[1][jj] - m[1]);
        float e2 = __expf(acc[2][jj] - m[2]);
        float e3 = __expf(acc[3][jj] - m[3]);
        ps[0] += e0; ps[1] += e1; ps[2] += e2; ps[3] += e3;
        float4 ev; ev.x = e0; ev.y = e1; ev.z = e2; ev.w = e3;
        *(float4*)&pT[j * 68 + tx * 4] = ev;
    }
#pragma unroll
    for (int ii = 0; ii < 4; ++ii) red[(tx * 4 + ii) * 17 + ty] = ps[ii];
    __syncthreads();
    float l[4];
#pragma unroll
    for (int ii = 0; ii < 4; ++ii) {
        float s = 0.f;
        for (int t = 0; t < 16; ++t) s += red[(tx * 4 + ii) * 17 + t];
        l[ii] = s;
    }

    if (ty == 0) {
#pragma unroll
        for (int ii = 0; ii < 4; ++ii) {
            int i = tx * 4 + ii;
            lse4[((size_t)bh * 4 + r) * 4096 + posl[i]] = m[ii] + __logf(l[ii]);
        }
    }

    // PV: rows i=tx*4..+4, cols c=ty*4..+4, K=128. V via uniform base +
    // 32-bit offsets (same fp32 words as before -> bit-identical chains).
    const char* vb8 = (const char*)v + ((size_t)bh << 20);   // uniform
    int coff = ty * 16;                                       // byte col offset
    float acc2[4][4];
#pragma unroll
    for (int i = 0; i < 4; ++i)
#pragma unroll
        for (int j = 0; j < 4; ++j) acc2[i][j] = 0.f;

    float4 p0 = *(const float4*)(vb8 + (voff[0] + coff));
    float4 p1 = *(const float4*)(vb8 + (voff[1] + coff));
    float4 p2 = *(const float4*)(vb8 + (voff[2] + coff));
    float4 p3 = *(const float4*)(vb8 + (voff[3] + coff));
    for (int j0 = 0; j0 < 128; j0 += 4) {
        float4 c0 = p0, c1 = p1, c2 = p2, c3 = p3;
        if (j0 + 4 < 128) {
            p0 = *(const float4*)(vb8 + (voff[j0 + 4] + coff));
            p1 = *(const float4*)(vb8 + (voff[j0 + 5] + coff));
            p2 = *(const float4*)(vb8 + (voff[j0 + 6] + coff));
            p3 = *(const float4*)(vb8 + (voff[j0 + 7] + coff));
        }
#define PVSTEP(JJ, CV)                                                       \
        {                                                                    \
            float a_[4];                                                     \
            *(float4*)a_ = *(const float4*)&pT[(j0 + (JJ)) * 68 + tx * 4];   \
            acc2[0][0] = fmaf(a_[0], CV.x, acc2[0][0]);                      \
            acc2[0][1] = fmaf(a_[0], CV.y, acc2[0][1]);                      \
            acc2[0][2] = fmaf(a_[0], CV.z, acc2[0][2]);                      \
            acc2[0][3] = fmaf(a_[0], CV.w, acc2[0][3]);                      \
            acc2[1][0] = fmaf(a_[1], CV.x, acc2[1][0]);                      \
            acc2[1][1] = fmaf(a_[1], CV.y, acc2[1][1]);                      \
            acc2[1][2] = fmaf(a_[1], CV.z, acc2[1][2]);                      \
            acc2[1][3] = fmaf(a_[1], CV.w, acc2[1][3]);                      \
            acc2[2][0] = fmaf(a_[2], CV.x, acc2[2][0]);                      \
            acc2[2][1] = fmaf(a_[2], CV.y, acc2[2][1]);                      \
            acc2[2][2] = fmaf(a_[2], CV.z, acc2[2][2]);                      \
            acc2[2][3] = fmaf(a_[2], CV.w, acc2[2][3]);                      \
            acc2[3][0] = fmaf(a_[3], CV.x, acc2[3][0]);                      \
            acc2[3][1] = fmaf(a_[3], CV.y, acc2[3][1]);                      \
            acc2[3][2] = fmaf(a_[3], CV.z, acc2[3][2]);                      \
            acc2[3][3] = fmaf(a_[3], CV.w, acc2[3][3]);                      \
        }
        PVSTEP(0, c0)
        PVSTEP(1, c1)
        PVSTEP(2, c2)
        PVSTEP(3, c3)
#undef PVSTEP
    }
#pragma unroll
    for (int ii = 0; ii < 4; ++ii) {
        int i = tx * 4 + ii;
        float rl = 1.0f / l[ii];
        size_t ob = (((size_t)bh * 4 + r) * 4096 + posl[i]) * 64 + ty * 4;
        float4 ov;
        ov.x = acc2[ii][0] * rl;
        ov.y = acc2[ii][1] * rl;
        ov.z = acc2[ii][2] * rl;
        ov.w = acc2[ii][3] * rl;
        *(float4*)&o4[ob] = ov;
    }
}

// ---------------------------------------------------------------------------
// Combine hash rounds (softmax over per-round lse). Grid 32768.
// ---------------------------------------------------------------------------
__global__ __launch_bounds__(256) void combine_kernel(const float* __restrict__ o4,
                                                      const float* __restrict__ lse4,
                                                      float* __restrict__ o_bt) {
    int tid = threadIdx.x;
    int gt = blockIdx.x * 4 + (tid >> 6);  // global token 0..131071
    int d = tid & 63;
    int bh = gt >> 12, p = gt & 4095;
    size_t base = ((size_t)bh * 4) * 4096 + p;
    float l0 = lse4[base];
    float l1 = lse4[base + 4096];
    float l2 = lse4[base + 8192];
    float l3 = lse4[base + 12288];
    float mm = fmaxf(fmaxf(l0, l1), fmaxf(l2, l3));
    float w0 = __expf(l0 - mm), w1 = __expf(l1 - mm);
    float w2 = __expf(l2 - mm), w3 = __expf(l3 - mm);
    float W = w0 + w1 + w2 + w3;
    size_t ob = (((size_t)bh * 4) * 4096 + p) * 64 + d;
    const size_t rs = (size_t)4096 * 64;
    float o = w0 * o4[ob]
            + w1 * o4[ob + rs]
            + w2 * o4[ob + 2 * rs]
            + w3 * o4[ob + 3 * rs];
    int b = bh >> 4, h = bh & 15;
    o_bt[((size_t)b * 4096 + p) * 1024 + h * 64 + d] = o / W;
}

// ---------------------------------------------------------------------------
extern "C" void kernel_launch(void* const* d_in, const int* in_sizes, int n_in,
                              void* d_out, int out_size, void* d_ws, size_t ws_size,
                              hipStream_t stream) {
    const float* x    = (const float*)d_in[0];   // queries (2,4096,1024)
    const float* Wqk  = (const float*)d_in[4];   // (1024,1024)
    const float* Wv   = (const float*)d_in[5];
    const float* Wout = (const float*)d_in[6];
    const float* bout = (const float*)d_in[7];   // (1024,)
    const float* rot  = (const float*)d_in[8];   // (64,4,32)
    float* out = (float*)d_out;

    char* ws = (char*)d_ws;
    float* qk32          = (float*)(ws);                        // 33,554,432 B (reused as o_bt)
    float* v             = (float*)(ws + 33554432);             // 33,554,432
    float* o4            = (float*)(ws + 67108864);             // 134,217,728
    float* lse4          = (float*)(ws + 201326592);            // 2,097,152
    int* keys            = (int*)(ws + 203423744);              // 2,097,152
    int* st_sorted       = (int*)(ws + 205520896);              // 2,097,152
    float* o_bt          = qk32;                                // alias: qk32 dead after attn

    proj2<<<1024, 256, 0, stream>>>(x, Wqk, Wv, qk32, v);
    bucket32<<<2048, 256, 0, stream>>>(qk32, rot, keys);
    countsort_kernel<<<128, 256, 0, stream>>>(keys, st_sorted);
    attn_kernel<<<8192, 256, 0, stream>>>(qk32, v, st_sorted, o4, lse4);
    combine_kernel<<<32768, 256, 0, stream>>>(o4, lse4, o_bt);
    sgemm_out<<<512, 256, 0, stream>>>(o_bt, Wout, out, bout);
}

// Round 8
// 1154.304 us; speedup vs baseline: 1.0147x; 1.0147x over previous
//
#include <hip/hip_runtime.h>
#include <hip/hip_bf16.h>
#include <math.h>

// B=2, N=4096, C=1024, HEADS=16, DH=64, BUCKET=64, N_HASHES=4, n_buckets=64
// BH=32, T=4096, 256 bins (r*64+b), 256 chunks of 64 slots per bh.
//
// NUMERICS CONTRACT: the discrete path — qk projection and bucket rotation —
// must be an ascending-k fp32 FMA chain per output element (replicates the
// numpy fp32 reference's argmax decisions). proj2/sgemm_out preserve that
// chain bit-for-bit: k = 0..1023 strictly ascending into ONE fp32 accumulator
// per output element (BK only regroups the memory staging, not the chain).
// bucket32 / countsort / attn / combine byte-identical to round 6/7.
//
// ROUND 8 (post-mortem r7: __launch_bounds__(256,4) forced VGPR to the
// 64-reg step -> acc[8][8] spilled to scratch -> WRITE_SIZE 65MB->320MB,
// proj2 420->469us. The BK=16 hypothesis was never tested - confounded):
//  * proj2/sgemm_out: KEEP BK=16, DROP the min-waves clamp
//    (__launch_bounds__(256) only). Expected ~104-120 VGPR (< 128 step)
//    -> still 4 waves/SIMD, no spill. Clean test of barrier amortization.

// ---------------------------------------------------------------------------
// Shared inner loop: 128x128 tile, BK=16, 256 threads, 8x8 micro-tile with
// split rows/cols (a@tx*4 & 64+tx*4, b@ty*4 & 64+ty*4): all LDS reads
// <=2-way bank aliasing (free). kk ascending 0..15 -> k ascending globally.
// ---------------------------------------------------------------------------
#define SG_COMPUTE(BUF)                                                      \
    {                                                                        \
        _Pragma("unroll")                                                    \
        for (int kk = 0; kk < 16; ++kk) {                                    \
            float a[8], b[8];                                                \
            *(float4*)&a[0] = *(const float4*)&As[BUF][kk][tx * 4];          \
            *(float4*)&a[4] = *(const float4*)&As[BUF][kk][64 + tx * 4];     \
            *(float4*)&b[0] = *(const float4*)&Bs[BUF][kk][ty * 4];          \
            *(float4*)&b[4] = *(const float4*)&Bs[BUF][kk][64 + ty * 4];     \
            _Pragma("unroll")                                                \
            for (int i = 0; i < 8; ++i)                                      \
                _Pragma("unroll")                                            \
                for (int j = 0; j < 8; ++j)                                  \
                    acc[i][j] = fmaf(a[i], b[j], acc[i][j]);                 \
        }                                                                    \
    }

// stage one BK=16 tile: each thread wrote k-cols lk..lk+3 and lk+8..lk+11
// of its row lr (av0/bv0 = k lk.., av1/bv1 = k lk+8..).
#define SG_STAGE(BUF)                                                        \
    {                                                                        \
        As[BUF][lk + 0][lr] = av0.x; As[BUF][lk + 1][lr] = av0.y;            \
        As[BUF][lk + 2][lr] = av0.z; As[BUF][lk + 3][lr] = av0.w;            \
        As[BUF][lk + 8][lr] = av1.x; As[BUF][lk + 9][lr] = av1.y;            \
        As[BUF][lk + 10][lr] = av1.z; As[BUF][lk + 11][lr] = av1.w;          \
        Bs[BUF][lk + 0][lr] = bv0.x; Bs[BUF][lk + 1][lr] = bv0.y;            \
        Bs[BUF][lk + 2][lr] = bv0.z; Bs[BUF][lk + 3][lr] = bv0.w;            \
        Bs[BUF][lk + 8][lr] = bv1.x; Bs[BUF][lk + 9][lr] = bv1.y;            \
        Bs[BUF][lk + 10][lr] = bv1.z; Bs[BUF][lk + 11][lr] = bv1.w;          \
    }

#define SG_LOAD(IT)                                                          \
    {                                                                        \
        av0 = *(const float4*)&pA[(IT) * 16];                                \
        av1 = *(const float4*)&pA[(IT) * 16 + 8];                            \
        bv0 = *(const float4*)&pB[(IT) * 16];                                \
        bv1 = *(const float4*)&pB[(IT) * 16 + 8];                            \
    }

// ---------------------------------------------------------------------------
// Fused projection: C[m, 0:2048] = x . [Wqk; Wv]^T, head-layout outputs.
// Grid 1024: swz=(id&7)*128+(id>>3); tm=swz>>4 (64 m-tiles), tn=swz&15.
// tn<8 -> Wqk -> outQK; tn>=8 -> Wv -> outV.
// ---------------------------------------------------------------------------
__global__ __launch_bounds__(256) void proj2(const float* __restrict__ A,
                                             const float* __restrict__ Wqk,
                                             const float* __restrict__ Wv,
                                             float* __restrict__ outQK,
                                             float* __restrict__ outV) {
    __shared__ float As[2][16][128];
    __shared__ float Bs[2][16][128];
    int tid = threadIdx.x;
    int tx = tid & 15, ty = tid >> 4;
    int id = blockIdx.x;                      // 0..1023
    int swz = (id & 7) * 128 + (id >> 3);
    int tm = swz >> 4;                        // 0..63
    int tn = swz & 15;                        // 0..15
    int m0 = tm * 128;
    const float* Wsel = (tn < 8) ? Wqk : Wv;
    float* dst = (tn < 8) ? outQK : outV;
    int nsel = (tn & 7) * 128;                // col base within selected matrix
    int lr = tid >> 1;                        // 0..127
    int lk = (tid & 1) * 4;                   // 0 or 4
    const float* pA = &A[(size_t)(m0 + lr) * 1024 + lk];
    const float* pB = &Wsel[(size_t)(nsel + lr) * 1024 + lk];
    float acc[8][8];
#pragma unroll
    for (int i = 0; i < 8; ++i)
#pragma unroll
        for (int j = 0; j < 8; ++j) acc[i][j] = 0.f;

    float4 av0, av1, bv0, bv1;
    SG_LOAD(0)
    SG_STAGE(0)
    __syncthreads();

    // 63 pipelined K-steps (BK=16); tile it lives in buffer it&1. Write of
    // buf[nxt] in iter it is safe: buf[nxt] was last READ in iter it-1,
    // sealed by iter it-1's barrier.
    for (int it = 0; it < 63; ++it) {
        int cur = it & 1;
        int nxt = cur ^ 1;
        SG_LOAD(it + 1)
        SG_COMPUTE(cur)
        SG_STAGE(nxt)
        __syncthreads();
    }
    // epilogue: tile 63 is in buffer 1; no barrier needed after.
    SG_COMPUTE(1)

    // epilogue: col group 0 -> head h0 = nsel>>6, d = ty*4..+3;
    //           col group 1 -> head h0+1, same d. float4 stores.
    int h0 = nsel >> 6;
#pragma unroll
    for (int i = 0; i < 8; ++i) {
        int m = m0 + ((i < 4) ? (tx * 4 + i) : (64 + tx * 4 + (i - 4)));
        int bb = m >> 12, t = m & 4095;
        float4 o0, o1;
        o0.x = acc[i][0]; o0.y = acc[i][1]; o0.z = acc[i][2]; o0.w = acc[i][3];
        o1.x = acc[i][4]; o1.y = acc[i][5]; o1.z = acc[i][6]; o1.w = acc[i][7];
        *(float4*)&dst[(((size_t)(bb * 16 + h0)) * 4096 + t) * 64 + ty * 4] = o0;
        *(float4*)&dst[(((size_t)(bb * 16 + h0 + 1)) * 4096 + t) * 64 + ty * 4] = o1;
    }
}

// ---------------------------------------------------------------------------
// Output GEMM: out[m][n] = o_bt . Wout^T + bout, row-major. Grid 512:
// swz=(id&7)*64+(id>>3); tm=swz>>3 (64 m-tiles), tn=swz&7 (8 n-tiles).
// ---------------------------------------------------------------------------
__global__ __launch_bounds__(256) void sgemm_out(const float* __restrict__ A,
                                                 const float* __restrict__ W,
                                                 float* __restrict__ out,
                                                 const float* __restrict__ bias) {
    __shared__ float As[2][16][128];
    __shared__ float Bs[2][16][128];
    int tid = threadIdx.x;
    int tx = tid & 15, ty = tid >> 4;
    int id = blockIdx.x;                      // 0..511
    int swz = (id & 7) * 64 + (id >> 3);
    int tm = swz >> 3;                        // 0..63
    int tn = swz & 7;                         // 0..7
    int m0 = tm * 128, n0 = tn * 128;
    int lr = tid >> 1;
    int lk = (tid & 1) * 4;
    const float* pA = &A[(size_t)(m0 + lr) * 1024 + lk];
    const float* pB = &W[(size_t)(n0 + lr) * 1024 + lk];
    float acc[8][8];
#pragma unroll
    for (int i = 0; i < 8; ++i)
#pragma unroll
        for (int j = 0; j < 8; ++j) acc[i][j] = 0.f;

    float4 av0, av1, bv0, bv1;
    SG_LOAD(0)
    SG_STAGE(0)
    __syncthreads();

    for (int it = 0; it < 63; ++it) {
        int cur = it & 1;
        int nxt = cur ^ 1;
        SG_LOAD(it + 1)
        SG_COMPUTE(cur)
        SG_STAGE(nxt)
        __syncthreads();
    }
    SG_COMPUTE(1)

    float4 bias0 = *(const float4*)&bias[n0 + ty * 4];
    float4 bias1 = *(const float4*)&bias[n0 + 64 + ty * 4];
#pragma unroll
    for (int i = 0; i < 8; ++i) {
        int m = m0 + ((i < 4) ? (tx * 4 + i) : (64 + tx * 4 + (i - 4)));
        float4 o0, o1;
        o0.x = acc[i][0] + bias0.x; o0.y = acc[i][1] + bias0.y;
        o0.z = acc[i][2] + bias0.z; o0.w = acc[i][3] + bias0.w;
        o1.x = acc[i][4] + bias1.x; o1.y = acc[i][5] + bias1.y;
        o1.z = acc[i][6] + bias1.z; o1.w = acc[i][7] + bias1.w;
        *(float4*)&out[(size_t)m * 1024 + n0 + ty * 4] = o0;
        *(float4*)&out[(size_t)m * 1024 + n0 + 64 + ty * 4] = o1;
    }
}
#undef SG_COMPUTE
#undef SG_STAGE
#undef SG_LOAD

// ---------------------------------------------------------------------------
// Bucketing (byte-identical to round 6).
// ---------------------------------------------------------------------------
__global__ __launch_bounds__(256) void bucket32(const float* __restrict__ qk,
                                                const float* __restrict__ rot,
                                                int* __restrict__ keys) {
    int tid = threadIdx.x;
    int blk = blockIdx.x;                 // 0..2047
    int token = (blk & 15) * 256 + tid;
    int r = (blk >> 4) & 3;               // block-uniform
    int bh = blk >> 6;                    // block-uniform
    const float* q = &qk[((size_t)bh * 4096 + token) * 64];
    float racc[32];
#pragma unroll
    for (int i = 0; i < 32; ++i) racc[i] = 0.f;
    for (int f0 = 0; f0 < 64; f0 += 4) {
        float4 qv = *(const float4*)&q[f0];
        const float* rp0 = &rot[(f0 + 0) * 128 + r * 32];
        const float* rp1 = rp0 + 128;
        const float* rp2 = rp0 + 256;
        const float* rp3 = rp0 + 384;
#pragma unroll
        for (int i = 0; i < 32; ++i) racc[i] = fmaf(qv.x, rp0[i], racc[i]);
#pragma unroll
        for (int i = 0; i < 32; ++i) racc[i] = fmaf(qv.y, rp1[i], racc[i]);
#pragma unroll
        for (int i = 0; i < 32; ++i) racc[i] = fmaf(qv.z, rp2[i], racc[i]);
#pragma unroll
        for (int i = 0; i < 32; ++i) racc[i] = fmaf(qv.w, rp3[i], racc[i]);
    }
    float best = -INFINITY;
    int bi = 0;
#pragma unroll
    for (int i = 0; i < 32; ++i) { if (racc[i] > best) { best = racc[i]; bi = i; } }
#pragma unroll
    for (int i = 0; i < 32; ++i) { float x = -racc[i]; if (x > best) { best = x; bi = 32 + i; } }
    int bin = r * 64 + bi;
    keys[(size_t)bh * 16384 + r * 4096 + token] = bin * 4096 + token;
}

// ---------------------------------------------------------------------------
// Stable counting sort per (bh, r) segment (byte-identical).
// ---------------------------------------------------------------------------
#define PST 257  // u16 row stride for pre[] (odd => spreads LDS banks)

__global__ __launch_bounds__(256) void countsort_kernel(const int* __restrict__ keys,
                                                        int* __restrict__ st_sorted) {
    __shared__ unsigned short pre[64 * PST];
    __shared__ unsigned char sbin[4096];
    __shared__ unsigned short sperm[4096];
    __shared__ int qsum[64 * 4];
    __shared__ int qoff[64 * 4];
    __shared__ int binOffset[64];

    int tid = threadIdx.x;
    int bh = blockIdx.x >> 2;
    int r = blockIdx.x & 3;
    const int* kb = &keys[(((size_t)bh * 4 + r) << 12)];

    for (int u = tid; u < 64 * PST; u += 256) pre[u] = 0;
    __syncthreads();

    int base = tid << 4;
#pragma unroll
    for (int u = 0; u < 4; ++u) {
        int4 kv = *(const int4*)&kb[base + u * 4];
        int b0 = (kv.x >> 12) & 63;
        int b1 = (kv.y >> 12) & 63;
        int b2 = (kv.z >> 12) & 63;
        int b3 = (kv.w >> 12) & 63;
        sbin[base + u * 4 + 0] = (unsigned char)b0;
        sbin[base + u * 4 + 1] = (unsigned char)b1;
        sbin[base + u * 4 + 2] = (unsigned char)b2;
        sbin[base + u * 4 + 3] = (unsigned char)b3;
        pre[b0 * PST + tid]++;
        pre[b1 * PST + tid]++;
        pre[b2 * PST + tid]++;
        pre[b3 * PST + tid]++;
    }
    __syncthreads();

    int b = tid & 63, q = tid >> 6;
    {
        int run = 0;
        for (int i = 0; i < 64; ++i) run += pre[b * PST + q * 64 + i];
        qsum[b * 4 + q] = run;
    }
    __syncthreads();

    if (tid < 64) {
        int s0 = qsum[tid * 4 + 0], s1 = qsum[tid * 4 + 1];
        int s2 = qsum[tid * 4 + 2], s3 = qsum[tid * 4 + 3];
        qoff[tid * 4 + 0] = 0;
        qoff[tid * 4 + 1] = s0;
        qoff[tid * 4 + 2] = s0 + s1;
        qoff[tid * 4 + 3] = s0 + s1 + s2;
        binOffset[tid] = s0 + s1 + s2 + s3;
    }
    __syncthreads();
    if (tid == 0) {
        int running = 0;
        for (int i = 0; i < 64; ++i) {
            int t = binOffset[i];
            binOffset[i] = running;
            running += t;
        }
    }
    __syncthreads();

    {
        int run2 = qoff[b * 4 + q];
        for (int i = 0; i < 64; ++i) {
            int idx = b * PST + q * 64 + i;
            int t = pre[idx];
            pre[idx] = (unsigned short)run2;
            run2 += t;
        }
    }
    __syncthreads();

#pragma unroll
    for (int k = 0; k < 16; ++k) {
        int bin = sbin[base + k];
        int off = pre[bin * PST + tid]++;
        sperm[binOffset[bin] + off] = (unsigned short)(base + k);
    }
    __syncthreads();

    int* ob = &st_sorted[(((size_t)bh * 4 + r) << 12)];
#pragma unroll
    for (int u = 0; u < 16; ++u) ob[u * 256 + tid] = (int)sperm[u * 256 + tid];
}

// ---------------------------------------------------------------------------
// Tiled chunked attention (byte-identical to round 6).
// ---------------------------------------------------------------------------
__global__ __launch_bounds__(256) void attn_kernel(const float* __restrict__ qk,
                                                   const float* __restrict__ v,
                                                   const int* __restrict__ st_sorted,
                                                   float* __restrict__ o4,
                                                   float* __restrict__ lse4) {
    __shared__ float bufA[128 * 68];  // phase1: kqt[f][row^swz] stride 132; phase2: pT[j][i] stride 68
    __shared__ float red[64 * 17];
    __shared__ int posl[128];
    __shared__ int voff[128];         // posl*256: byte offset of V row
    __shared__ float invl[128];

    int tid = threadIdx.x;
    int bh = blockIdx.x >> 8;
    int c = blockIdx.x & 255;
    int r = c >> 6;
    int pc = (c + 255) & 255;
    const int* stb = &st_sorted[(size_t)bh * 16384];
    if (tid < 64) {
        int p = stb[c * 64 + tid];
        posl[tid] = p;
        voff[tid] = p << 8;           // *64 floats *4 bytes
    } else if (tid < 128) {
        int p = stb[pc * 64 + (tid - 64)];
        posl[tid] = p;
        voff[tid] = p << 8;
    }
    __syncthreads();

    // stage qk -> kqt transposed, XOR-swizzled: row' = row ^ (4*((f>>2)&7)).
    float* kqt = bufA;
#pragma unroll
    for (int u = 0; u < 8; ++u) {
        int flat = u * 256 + tid;              // 0..2047 float4 units
        int row = flat >> 4;
        int f4 = (flat & 15) * 4;
        size_t gbase = ((size_t)bh * 4096 + posl[row]) * 64 + f4;
        float4 qv = *(const float4*)&qk[gbase];
        int rw = row ^ ((((f4 >> 2)) & 7) << 2);
        kqt[(f4 + 0) * 132 + rw] = qv.x;
        kqt[(f4 + 1) * 132 + rw] = qv.y;
        kqt[(f4 + 2) * 132 + rw] = qv.z;
        kqt[(f4 + 3) * 132 + rw] = qv.w;
    }
    __syncthreads();

    if (tid < 128) {
        float ss = 0.f;
        for (int f = 0; f < 64; ++f) {
            int s = ((f >> 2) & 7) << 2;
            float x = kqt[f * 132 + (tid ^ s)];
            ss += x * x;
        }
        invl[tid] = 1.0f / fmaxf(sqrtf(ss), 1e-12f);
    }
    __syncthreads();

    int tx = tid & 15, ty = tid >> 4;   // rows i=tx*4..+4 (queries), cols j=ty*8..+8 (keys)
    float acc[4][8];
#pragma unroll
    for (int i = 0; i < 4; ++i)
#pragma unroll
        for (int j = 0; j < 8; ++j) acc[i][j] = 0.f;
#pragma unroll
    for (int f = 0; f < 64; ++f) {
        int s = ((f >> 2) & 7) << 2;
        float a[4], b[8];
        *(float4*)a = *(const float4*)&kqt[f * 132 + ((tx * 4) ^ s)];
        *(float4*)&b[0] = *(const float4*)&kqt[f * 132 + ((ty * 8) ^ s)];
        *(float4*)&b[4] = *(const float4*)&kqt[f * 132 + ((ty * 8 + 4) ^ s)];
#pragma unroll
        for (int i = 0; i < 4; ++i)
#pragma unroll
            for (int j = 0; j < 8; ++j) acc[i][j] = fmaf(a[i], b[j], acc[i][j]);
    }

    // scale + self-mask
    int qp[4];
#pragma unroll
    for (int ii = 0; ii < 4; ++ii) qp[ii] = posl[tx * 4 + ii];
#pragma unroll
    for (int jj = 0; jj < 8; ++jj) {
        int j = ty * 8 + jj;
        float sc = invl[j] * 0.125f;
        int kp = posl[j];
#pragma unroll
        for (int ii = 0; ii < 4; ++ii) {
            float x = acc[ii][jj] * sc;
            acc[ii][jj] = (qp[ii] == kp) ? -5e4f : x;
        }
    }

    // row max across the 16 ty-groups
#pragma unroll
    for (int ii = 0; ii < 4; ++ii) {
        float pm = acc[ii][0];
#pragma unroll
        for (int jj = 1; jj < 8; ++jj) pm = fmaxf(pm, acc[ii][jj]);
        red[(tx * 4 + ii) * 17 + ty] = pm;
    }
    __syncthreads();
    float m[4];
#pragma unroll
    for (int ii = 0; ii < 4; ++ii) {
        float mm = red[(tx * 4 + ii) * 17 + 0];
        for (int t = 1; t < 16; ++t) mm = fmaxf(mm, red[(tx * 4 + ii) * 17 + t]);
        m[ii] = mm;
    }
    __syncthreads();  // max reads done before red reuse + kqt reads done before pT overwrite

    // exp, store transposed probs as float4 (conflict-free), partial sums.
    float* pT = bufA;
    float ps[4] = {0.f, 0.f, 0.f, 0.f};
#pragma unroll
    for (int jj = 0; jj < 8; ++jj) {
        int j = ty * 8 + jj;
        float e0 = __expf(acc[0][jj] - m[0]);
        float e1 = __expf(acc[1][jj] - m[1]);
        float e2 = __expf(acc[2][jj] - m[2]);
        float e3 = __expf(acc[3][jj] - m[3]);
        ps[0] += e0; ps[1] += e1; ps[2] += e2; ps[3] += e3;
        float4 ev; ev.x = e0; ev.y = e1; ev.z = e2; ev.w = e3;
        *(float4*)&pT[j * 68 + tx * 4] = ev;
    }
#pragma unroll
    for (int ii = 0; ii < 4; ++ii) red[(tx * 4 + ii) * 17 + ty] = ps[ii];
    __syncthreads();
    float l[4];
#pragma unroll
    for (int ii = 0; ii < 4; ++ii) {
        float s = 0.f;
        for (int t = 0; t < 16; ++t) s += red[(tx * 4 + ii) * 17 + t];
        l[ii] = s;
    }

    if (ty == 0) {
#pragma unroll
        for (int ii = 0; ii < 4; ++ii) {
            int i = tx * 4 + ii;
            lse4[((size_t)bh * 4 + r) * 4096 + posl[i]] = m[ii] + __logf(l[ii]);
        }
    }

    // PV: rows i=tx*4..+4, cols c=ty*4..+4, K=128. V via uniform base +
    // 32-bit offsets (same fp32 words as before -> bit-identical chains).
    const char* vb8 = (const char*)v + ((size_t)bh << 20);   // uniform
    int coff = ty * 16;                                       // byte col offset
    float acc2[4][4];
#pragma unroll
    for (int i = 0; i < 4; ++i)
#pragma unroll
        for (int j = 0; j < 4; ++j) acc2[i][j] = 0.f;

    float4 p0 = *(const float4*)(vb8 + (voff[0] + coff));
    float4 p1 = *(const float4*)(vb8 + (voff[1] + coff));
    float4 p2 = *(const float4*)(vb8 + (voff[2] + coff));
    float4 p3 = *(const float4*)(vb8 + (voff[3] + coff));
    for (int j0 = 0; j0 < 128; j0 += 4) {
        float4 c0 = p0, c1 = p1, c2 = p2, c3 = p3;
        if (j0 + 4 < 128) {
            p0 = *(const float4*)(vb8 + (voff[j0 + 4] + coff));
            p1 = *(const float4*)(vb8 + (voff[j0 + 5] + coff));
            p2 = *(const float4*)(vb8 + (voff[j0 + 6] + coff));
            p3 = *(const float4*)(vb8 + (voff[j0 + 7] + coff));
        }
#define PVSTEP(JJ, CV)                                                       \
        {                                                                    \
            float a_[4];                                                     \
            *(float4*)a_ = *(const float4*)&pT[(j0 + (JJ)) * 68 + tx * 4];   \
            acc2[0][0] = fmaf(a_[0], CV.x, acc2[0][0]);                      \
            acc2[0][1] = fmaf(a_[0], CV.y, acc2[0][1]);                      \
            acc2[0][2] = fmaf(a_[0], CV.z, acc2[0][2]);                      \
            acc2[0][3] = fmaf(a_[0], CV.w, acc2[0][3]);                      \
            acc2[1][0] = fmaf(a_[1], CV.x, acc2[1][0]);                      \
            acc2[1][1] = fmaf(a_[1], CV.y, acc2[1][1]);                      \
            acc2[1][2] = fmaf(a_[1], CV.z, acc2[1][2]);                      \
            acc2[1][3] = fmaf(a_[1], CV.w, acc2[1][3]);                      \
            acc2[2][0] = fmaf(a_[2], CV.x, acc2[2][0]);                      \
            acc2[2][1] = fmaf(a_[2], CV.y, acc2[2][1]);                      \
            acc2[2][2] = fmaf(a_[2], CV.z, acc2[2][2]);                      \
            acc2[2][3] = fmaf(a_[2], CV.w, acc2[2][3]);                      \
            acc2[3][0] = fmaf(a_[3], CV.x, acc2[3][0]);                      \
            acc2[3][1] = fmaf(a_[3], CV.y, acc2[3][1]);                      \
            acc2[3][2] = fmaf(a_[3], CV.z, acc2[3][2]);                      \
            acc2[3][3] = fmaf(a_[3], CV.w, acc2[3][3]);                      \
        }
        PVSTEP(0, c0)
        PVSTEP(1, c1)
        PVSTEP(2, c2)
        PVSTEP(3, c3)
#undef PVSTEP
    }
#pragma unroll
    for (int ii = 0; ii < 4; ++ii) {
        int i = tx * 4 + ii;
        float rl = 1.0f / l[ii];
        size_t ob = (((size_t)bh * 4 + r) * 4096 + posl[i]) * 64 + ty * 4;
        float4 ov;
        ov.x = acc2[ii][0] * rl;
        ov.y = acc2[ii][1] * rl;
        ov.z = acc2[ii][2] * rl;
        ov.w = acc2[ii][3] * rl;
        *(float4*)&o4[ob] = ov;
    }
}

// ---------------------------------------------------------------------------
// Combine hash rounds (softmax over per-round lse). Grid 32768.
// ---------------------------------------------------------------------------
__global__ __launch_bounds__(256) void combine_kernel(const float* __restrict__ o4,
                                                      const float* __restrict__ lse4,
                                                      float* __restrict__ o_bt) {
    int tid = threadIdx.x;
    int gt = blockIdx.x * 4 + (tid >> 6);  // global token 0..131071
    int d = tid & 63;
    int bh = gt >> 12, p = gt & 4095;
    size_t base = ((size_t)bh * 4) * 4096 + p;
    float l0 = lse4[base];
    float l1 = lse4[base + 4096];
    float l2 = lse4[base + 8192];
    float l3 = lse4[base + 12288];
    float mm = fmaxf(fmaxf(l0, l1), fmaxf(l2, l3));
    float w0 = __expf(l0 - mm), w1 = __expf(l1 - mm);
    float w2 = __expf(l2 - mm), w3 = __expf(l3 - mm);
    float W = w0 + w1 + w2 + w3;
    size_t ob = (((size_t)bh * 4) * 4096 + p) * 64 + d;
    const size_t rs = (size_t)4096 * 64;
    float o = w0 * o4[ob]
            + w1 * o4[ob + rs]
            + w2 * o4[ob + 2 * rs]
            + w3 * o4[ob + 3 * rs];
    int b = bh >> 4, h = bh & 15;
    o_bt[((size_t)b * 4096 + p) * 1024 + h * 64 + d] = o / W;
}

// ---------------------------------------------------------------------------
extern "C" void kernel_launch(void* const* d_in, const int* in_sizes, int n_in,
                              void* d_out, int out_size, void* d_ws, size_t ws_size,
                              hipStream_t stream) {
    const float* x    = (const float*)d_in[0];   // queries (2,4096,1024)
    const float* Wqk  = (const float*)d_in[4];   // (1024,1024)
    const float* Wv   = (const float*)d_in[5];
    const float* Wout = (const float*)d_in[6];
    const float* bout = (const float*)d_in[7];   // (1024,)
    const float* rot  = (const float*)d_in[8];   // (64,4,32)
    float* out = (float*)d_out;

    char* ws = (char*)d_ws;
    float* qk32          = (float*)(ws);                        // 33,554,432 B (reused as o_bt)
    float* v             = (float*)(ws + 33554432);             // 33,554,432
    float* o4            = (float*)(ws + 67108864);             // 134,217,728
    float* lse4          = (float*)(ws + 201326592);            // 2,097,152
    int* keys            = (int*)(ws + 203423744);              // 2,097,152
    int* st_sorted       = (int*)(ws + 205520896);              // 2,097,152
    float* o_bt          = qk32;                                // alias: qk32 dead after attn

    proj2<<<1024, 256, 0, stream>>>(x, Wqk, Wv, qk32, v);
    bucket32<<<2048, 256, 0, stream>>>(qk32, rot, keys);
    countsort_kernel<<<128, 256, 0, stream>>>(keys, st_sorted);
    attn_kernel<<<8192, 256, 0, stream>>>(qk32, v, st_sorted, o4, lse4);
    combine_kernel<<<32768, 256, 0, stream>>>(o4, lse4, o_bt);
    sgemm_out<<<512, 256, 0, stream>>>(o_bt, Wout, out, bout);
}

// Round 9
// 1089.624 us; speedup vs baseline: 1.0749x; 1.0594x over previous
//
#include <hip/hip_runtime.h>
#include <hip/hip_bf16.h>
#include <math.h>

// B=2, N=4096, C=1024, HEADS=16, DH=64, BUCKET=64, N_HASHES=4, n_buckets=64
// BH=32, T=4096, 256 bins (r*64+b), 256 chunks of 64 slots per bh.
//
// NUMERICS CONTRACT: the discrete path — qk projection and bucket rotation —
// must be an ascending-k fp32 FMA chain per output element (replicates the
// numpy fp32 reference's argmax decisions). proj2/sgemm_out preserve that
// chain bit-for-bit. The sort and self-mask depend ONLY on that path.
// invl / dots / softmax / PV are continuous, tolerance-checked — the invl
// reduction was reordered this round (2-way partial), which is safe.
//
// ROUND 9 (post-mortem r7/r8: BK=16 refuted — VGPR 136 > 128 step cut
// residency; BK=8 @ 88 VGPR is the register-feasible optimum):
//  * proj2/sgemm_out: exact round-6 configuration restored (BK=8, 128x128
//    tile, split-row/col fragments, m-major XCD swizzle, 1 barrier/K-step).
//  * attn (issue-bound at 92-97% VALUBusy -> instruction diet):
//    (a) invl pass: 128 threads x 64 serial reads -> 256 threads x 32 reads
//        + 2-way combine via red[] (was half-idle, serial chain halved).
//    (b) QK loop restructured over the 8 XOR-swizzle phases so the 3 xored
//        base addresses are computed once per phase, not per f. FMA order
//        (f ascending) unchanged.

// ---------------------------------------------------------------------------
// Shared inner loop: 128x128 tile, BK=8, 256 threads, 8x8 micro-tile with
// split rows/cols. All LDS reads <=2-way bank aliasing (free).
// ---------------------------------------------------------------------------
#define SG_COMPUTE(BUF)                                                      \
    {                                                                        \
        _Pragma("unroll")                                                    \
        for (int kk = 0; kk < 8; ++kk) {                                     \
            float a[8], b[8];                                                \
            *(float4*)&a[0] = *(const float4*)&As[BUF][kk][tx * 4];          \
            *(float4*)&a[4] = *(const float4*)&As[BUF][kk][64 + tx * 4];     \
            *(float4*)&b[0] = *(const float4*)&Bs[BUF][kk][ty * 4];          \
            *(float4*)&b[4] = *(const float4*)&Bs[BUF][kk][64 + ty * 4];     \
            _Pragma("unroll")                                                \
            for (int i = 0; i < 8; ++i)                                      \
                _Pragma("unroll")                                            \
                for (int j = 0; j < 8; ++j)                                  \
                    acc[i][j] = fmaf(a[i], b[j], acc[i][j]);                 \
        }                                                                    \
    }

#define SG_STAGE(BUF)                                                        \
    {                                                                        \
        As[BUF][lk + 0][lr] = av.x; As[BUF][lk + 1][lr] = av.y;              \
        As[BUF][lk + 2][lr] = av.z; As[BUF][lk + 3][lr] = av.w;              \
        Bs[BUF][lk + 0][lr] = bv.x; Bs[BUF][lk + 1][lr] = bv.y;              \
        Bs[BUF][lk + 2][lr] = bv.z; Bs[BUF][lk + 3][lr] = bv.w;              \
    }

// ---------------------------------------------------------------------------
// Fused projection: C[m, 0:2048] = x . [Wqk; Wv]^T, head-layout outputs.
// Grid 1024: swz=(id&7)*128+(id>>3); tm=swz>>4 (64 m-tiles), tn=swz&15.
// tn<8 -> Wqk -> outQK; tn>=8 -> Wv -> outV. Per-XCD A chunk = 4MB (L2-fit).
// ---------------------------------------------------------------------------
__global__ __launch_bounds__(256) void proj2(const float* __restrict__ A,
                                             const float* __restrict__ Wqk,
                                             const float* __restrict__ Wv,
                                             float* __restrict__ outQK,
                                             float* __restrict__ outV) {
    __shared__ float As[2][8][128];
    __shared__ float Bs[2][8][128];
    int tid = threadIdx.x;
    int tx = tid & 15, ty = tid >> 4;
    int id = blockIdx.x;                      // 0..1023
    int swz = (id & 7) * 128 + (id >> 3);
    int tm = swz >> 4;                        // 0..63
    int tn = swz & 15;                        // 0..15
    int m0 = tm * 128;
    const float* Wsel = (tn < 8) ? Wqk : Wv;
    float* dst = (tn < 8) ? outQK : outV;
    int nsel = (tn & 7) * 128;                // col base within selected matrix
    int lr = tid >> 1;                        // 0..127
    int lk = (tid & 1) * 4;
    const float* pA = &A[(size_t)(m0 + lr) * 1024 + lk];
    const float* pB = &Wsel[(size_t)(nsel + lr) * 1024 + lk];
    float acc[8][8];
#pragma unroll
    for (int i = 0; i < 8; ++i)
#pragma unroll
        for (int j = 0; j < 8; ++j) acc[i][j] = 0.f;

    float4 av = *(const float4*)&pA[0];
    float4 bv = *(const float4*)&pB[0];
    SG_STAGE(0)
    __syncthreads();

    for (int it = 0; it < 127; ++it) {
        int cur = it & 1;
        int nxt = cur ^ 1;
        av = *(const float4*)&pA[(it + 1) * 8];
        bv = *(const float4*)&pB[(it + 1) * 8];
        SG_COMPUTE(cur)
        SG_STAGE(nxt)
        __syncthreads();
    }
    SG_COMPUTE(1)

    // epilogue: col group 0 -> head h0 = nsel>>6, d = ty*4..+3;
    //           col group 1 -> head h0+1, same d. float4 stores.
    int h0 = nsel >> 6;
#pragma unroll
    for (int i = 0; i < 8; ++i) {
        int m = m0 + ((i < 4) ? (tx * 4 + i) : (64 + tx * 4 + (i - 4)));
        int bb = m >> 12, t = m & 4095;
        float4 o0, o1;
        o0.x = acc[i][0]; o0.y = acc[i][1]; o0.z = acc[i][2]; o0.w = acc[i][3];
        o1.x = acc[i][4]; o1.y = acc[i][5]; o1.z = acc[i][6]; o1.w = acc[i][7];
        *(float4*)&dst[(((size_t)(bb * 16 + h0)) * 4096 + t) * 64 + ty * 4] = o0;
        *(float4*)&dst[(((size_t)(bb * 16 + h0 + 1)) * 4096 + t) * 64 + ty * 4] = o1;
    }
}

// ---------------------------------------------------------------------------
// Output GEMM: out[m][n] = o_bt . Wout^T + bout, row-major. Grid 512:
// swz=(id&7)*64+(id>>3); tm=swz>>3 (64 m-tiles), tn=swz&7 (8 n-tiles).
// ---------------------------------------------------------------------------
__global__ __launch_bounds__(256) void sgemm_out(const float* __restrict__ A,
                                                 const float* __restrict__ W,
                                                 float* __restrict__ out,
                                                 const float* __restrict__ bias) {
    __shared__ float As[2][8][128];
    __shared__ float Bs[2][8][128];
    int tid = threadIdx.x;
    int tx = tid & 15, ty = tid >> 4;
    int id = blockIdx.x;                      // 0..511
    int swz = (id & 7) * 64 + (id >> 3);
    int tm = swz >> 3;                        // 0..63
    int tn = swz & 7;                         // 0..7
    int m0 = tm * 128, n0 = tn * 128;
    int lr = tid >> 1;
    int lk = (tid & 1) * 4;
    const float* pA = &A[(size_t)(m0 + lr) * 1024 + lk];
    const float* pB = &W[(size_t)(n0 + lr) * 1024 + lk];
    float acc[8][8];
#pragma unroll
    for (int i = 0; i < 8; ++i)
#pragma unroll
        for (int j = 0; j < 8; ++j) acc[i][j] = 0.f;

    float4 av = *(const float4*)&pA[0];
    float4 bv = *(const float4*)&pB[0];
    SG_STAGE(0)
    __syncthreads();

    for (int it = 0; it < 127; ++it) {
        int cur = it & 1;
        int nxt = cur ^ 1;
        av = *(const float4*)&pA[(it + 1) * 8];
        bv = *(const float4*)&pB[(it + 1) * 8];
        SG_COMPUTE(cur)
        SG_STAGE(nxt)
        __syncthreads();
    }
    SG_COMPUTE(1)

    float4 bias0 = *(const float4*)&bias[n0 + ty * 4];
    float4 bias1 = *(const float4*)&bias[n0 + 64 + ty * 4];
#pragma unroll
    for (int i = 0; i < 8; ++i) {
        int m = m0 + ((i < 4) ? (tx * 4 + i) : (64 + tx * 4 + (i - 4)));
        float4 o0, o1;
        o0.x = acc[i][0] + bias0.x; o0.y = acc[i][1] + bias0.y;
        o0.z = acc[i][2] + bias0.z; o0.w = acc[i][3] + bias0.w;
        o1.x = acc[i][4] + bias1.x; o1.y = acc[i][5] + bias1.y;
        o1.z = acc[i][6] + bias1.z; o1.w = acc[i][7] + bias1.w;
        *(float4*)&out[(size_t)m * 1024 + n0 + ty * 4] = o0;
        *(float4*)&out[(size_t)m * 1024 + n0 + 64 + ty * 4] = o1;
    }
}
#undef SG_COMPUTE
#undef SG_STAGE

// ---------------------------------------------------------------------------
// Bucketing (byte-identical to round 6).
// ---------------------------------------------------------------------------
__global__ __launch_bounds__(256) void bucket32(const float* __restrict__ qk,
                                                const float* __restrict__ rot,
                                                int* __restrict__ keys) {
    int tid = threadIdx.x;
    int blk = blockIdx.x;                 // 0..2047
    int token = (blk & 15) * 256 + tid;
    int r = (blk >> 4) & 3;               // block-uniform
    int bh = blk >> 6;                    // block-uniform
    const float* q = &qk[((size_t)bh * 4096 + token) * 64];
    float racc[32];
#pragma unroll
    for (int i = 0; i < 32; ++i) racc[i] = 0.f;
    for (int f0 = 0; f0 < 64; f0 += 4) {
        float4 qv = *(const float4*)&q[f0];
        const float* rp0 = &rot[(f0 + 0) * 128 + r * 32];
        const float* rp1 = rp0 + 128;
        const float* rp2 = rp0 + 256;
        const float* rp3 = rp0 + 384;
#pragma unroll
        for (int i = 0; i < 32; ++i) racc[i] = fmaf(qv.x, rp0[i], racc[i]);
#pragma unroll
        for (int i = 0; i < 32; ++i) racc[i] = fmaf(qv.y, rp1[i], racc[i]);
#pragma unroll
        for (int i = 0; i < 32; ++i) racc[i] = fmaf(qv.z, rp2[i], racc[i]);
#pragma unroll
        for (int i = 0; i < 32; ++i) racc[i] = fmaf(qv.w, rp3[i], racc[i]);
    }
    float best = -INFINITY;
    int bi = 0;
#pragma unroll
    for (int i = 0; i < 32; ++i) { if (racc[i] > best) { best = racc[i]; bi = i; } }
#pragma unroll
    for (int i = 0; i < 32; ++i) { float x = -racc[i]; if (x > best) { best = x; bi = 32 + i; } }
    int bin = r * 64 + bi;
    keys[(size_t)bh * 16384 + r * 4096 + token] = bin * 4096 + token;
}

// ---------------------------------------------------------------------------
// Stable counting sort per (bh, r) segment (byte-identical).
// ---------------------------------------------------------------------------
#define PST 257  // u16 row stride for pre[] (odd => spreads LDS banks)

__global__ __launch_bounds__(256) void countsort_kernel(const int* __restrict__ keys,
                                                        int* __restrict__ st_sorted) {
    __shared__ unsigned short pre[64 * PST];
    __shared__ unsigned char sbin[4096];
    __shared__ unsigned short sperm[4096];
    __shared__ int qsum[64 * 4];
    __shared__ int qoff[64 * 4];
    __shared__ int binOffset[64];

    int tid = threadIdx.x;
    int bh = blockIdx.x >> 2;
    int r = blockIdx.x & 3;
    const int* kb = &keys[(((size_t)bh * 4 + r) << 12)];

    for (int u = tid; u < 64 * PST; u += 256) pre[u] = 0;
    __syncthreads();

    int base = tid << 4;
#pragma unroll
    for (int u = 0; u < 4; ++u) {
        int4 kv = *(const int4*)&kb[base + u * 4];
        int b0 = (kv.x >> 12) & 63;
        int b1 = (kv.y >> 12) & 63;
        int b2 = (kv.z >> 12) & 63;
        int b3 = (kv.w >> 12) & 63;
        sbin[base + u * 4 + 0] = (unsigned char)b0;
        sbin[base + u * 4 + 1] = (unsigned char)b1;
        sbin[base + u * 4 + 2] = (unsigned char)b2;
        sbin[base + u * 4 + 3] = (unsigned char)b3;
        pre[b0 * PST + tid]++;
        pre[b1 * PST + tid]++;
        pre[b2 * PST + tid]++;
        pre[b3 * PST + tid]++;
    }
    __syncthreads();

    int b = tid & 63, q = tid >> 6;
    {
        int run = 0;
        for (int i = 0; i < 64; ++i) run += pre[b * PST + q * 64 + i];
        qsum[b * 4 + q] = run;
    }
    __syncthreads();

    if (tid < 64) {
        int s0 = qsum[tid * 4 + 0], s1 = qsum[tid * 4 + 1];
        int s2 = qsum[tid * 4 + 2], s3 = qsum[tid * 4 + 3];
        qoff[tid * 4 + 0] = 0;
        qoff[tid * 4 + 1] = s0;
        qoff[tid * 4 + 2] = s0 + s1;
        qoff[tid * 4 + 3] = s0 + s1 + s2;
        binOffset[tid] = s0 + s1 + s2 + s3;
    }
    __syncthreads();
    if (tid == 0) {
        int running = 0;
        for (int i = 0; i < 64; ++i) {
            int t = binOffset[i];
            binOffset[i] = running;
            running += t;
        }
    }
    __syncthreads();

    {
        int run2 = qoff[b * 4 + q];
        for (int i = 0; i < 64; ++i) {
            int idx = b * PST + q * 64 + i;
            int t = pre[idx];
            pre[idx] = (unsigned short)run2;
            run2 += t;
        }
    }
    __syncthreads();

#pragma unroll
    for (int k = 0; k < 16; ++k) {
        int bin = sbin[base + k];
        int off = pre[bin * PST + tid]++;
        sperm[binOffset[bin] + off] = (unsigned short)(base + k);
    }
    __syncthreads();

    int* ob = &st_sorted[(((size_t)bh * 4 + r) << 12)];
#pragma unroll
    for (int u = 0; u < 16; ++u) ob[u * 256 + tid] = (int)sperm[u * 256 + tid];
}

// ---------------------------------------------------------------------------
// Tiled chunked attention. Grid 8192 = 32 bh * 256 chunks. Block 256.
// This round: invl computed by all 256 threads (2-way partial; continuous
// path, reorder safe); QK loop grouped by swizzle phase (address hoisting).
// QK/PV FMA orders unchanged.
// ---------------------------------------------------------------------------
__global__ __launch_bounds__(256) void attn_kernel(const float* __restrict__ qk,
                                                   const float* __restrict__ v,
                                                   const int* __restrict__ st_sorted,
                                                   float* __restrict__ o4,
                                                   float* __restrict__ lse4) {
    __shared__ float bufA[128 * 68];  // phase1: kqt[f][row^swz] stride 132; phase2: pT[j][i] stride 68
    __shared__ float red[64 * 17];
    __shared__ int posl[128];
    __shared__ int voff[128];         // posl*256: byte offset of V row
    __shared__ float invl[128];

    int tid = threadIdx.x;
    int bh = blockIdx.x >> 8;
    int c = blockIdx.x & 255;
    int r = c >> 6;
    int pc = (c + 255) & 255;
    const int* stb = &st_sorted[(size_t)bh * 16384];
    if (tid < 64) {
        int p = stb[c * 64 + tid];
        posl[tid] = p;
        voff[tid] = p << 8;           // *64 floats *4 bytes
    } else if (tid < 128) {
        int p = stb[pc * 64 + (tid - 64)];
        posl[tid] = p;
        voff[tid] = p << 8;
    }
    __syncthreads();

    // stage qk -> kqt transposed, XOR-swizzled: row' = row ^ (4*((f>>2)&7)).
    float* kqt = bufA;
#pragma unroll
    for (int u = 0; u < 8; ++u) {
        int flat = u * 256 + tid;              // 0..2047 float4 units
        int row = flat >> 4;
        int f4 = (flat & 15) * 4;
        size_t gbase = ((size_t)bh * 4096 + posl[row]) * 64 + f4;
        float4 qv = *(const float4*)&qk[gbase];
        int rw = row ^ ((((f4 >> 2)) & 7) << 2);
        kqt[(f4 + 0) * 132 + rw] = qv.x;
        kqt[(f4 + 1) * 132 + rw] = qv.y;
        kqt[(f4 + 2) * 132 + rw] = qv.z;
        kqt[(f4 + 3) * 132 + rw] = qv.w;
    }
    __syncthreads();

    // invl: 256 threads, 2 halves per row (row = tid&127, half = tid>>7).
    // Partials in red[row*2+h]; combine by 128 threads. Continuous path —
    // reduction order change is tolerance-safe (sort/mask don't use invl).
    {
        int row = tid & 127, hh = tid >> 7;
        float ss = 0.f;
#pragma unroll
        for (int e = 0; e < 32; ++e) {
            int f = hh * 32 + e;
            int s = ((f >> 2) & 7) << 2;
            float x = kqt[f * 132 + (row ^ s)];
            ss += x * x;
        }
        red[row * 2 + hh] = ss;
    }
    __syncthreads();
    if (tid < 128) {
        invl[tid] = 1.0f / fmaxf(sqrtf(red[tid * 2] + red[tid * 2 + 1]), 1e-12f);
    }
    __syncthreads();

    int tx = tid & 15, ty = tid >> 4;   // rows i=tx*4..+4 (queries), cols j=ty*8..+8 (keys)
    float acc[4][8];
#pragma unroll
    for (int i = 0; i < 4; ++i)
#pragma unroll
        for (int j = 0; j < 8; ++j) acc[i][j] = 0.f;
    // QK grouped by swizzle phase g (s constant per g): 3 xored bases hoisted
    // per phase. f = g*4+e ascending — FMA order identical to prior rounds.
#pragma unroll
    for (int g = 0; g < 16; ++g) {
        int s = (g & 7) << 2;
        const float* pa_ = &kqt[(tx * 4) ^ s];
        const float* pb0_ = &kqt[(ty * 8) ^ s];
        const float* pb1_ = &kqt[(ty * 8 + 4) ^ s];
#pragma unroll
        for (int e = 0; e < 4; ++e) {
            int f = g * 4 + e;
            float a[4], b[8];
            *(float4*)a = *(const float4*)&pa_[f * 132];
            *(float4*)&b[0] = *(const float4*)&pb0_[f * 132];
            *(float4*)&b[4] = *(const float4*)&pb1_[f * 132];
#pragma unroll
            for (int i = 0; i < 4; ++i)
#pragma unroll
                for (int j = 0; j < 8; ++j) acc[i][j] = fmaf(a[i], b[j], acc[i][j]);
        }
    }

    // scale + self-mask
    int qp[4];
#pragma unroll
    for (int ii = 0; ii < 4; ++ii) qp[ii] = posl[tx * 4 + ii];
#pragma unroll
    for (int jj = 0; jj < 8; ++jj) {
        int j = ty * 8 + jj;
        float sc = invl[j] * 0.125f;
        int kp = posl[j];
#pragma unroll
        for (int ii = 0; ii < 4; ++ii) {
            float x = acc[ii][jj] * sc;
            acc[ii][jj] = (qp[ii] == kp) ? -5e4f : x;
        }
    }

    // row max across the 16 ty-groups
#pragma unroll
    for (int ii = 0; ii < 4; ++ii) {
        float pm = acc[ii][0];
#pragma unroll
        for (int jj = 1; jj < 8; ++jj) pm = fmaxf(pm, acc[ii][jj]);
        red[(tx * 4 + ii) * 17 + ty] = pm;
    }
    __syncthreads();
    float m[4];
#pragma unroll
    for (int ii = 0; ii < 4; ++ii) {
        float mm = red[(tx * 4 + ii) * 17 + 0];
        for (int t = 1; t < 16; ++t) mm = fmaxf(mm, red[(tx * 4 + ii) * 17 + t]);
        m[ii] = mm;
    }
    __syncthreads();  // max reads done before red reuse + kqt reads done before pT overwrite

    // exp, store transposed probs as float4 (conflict-free), partial sums.
    float* pT = bufA;
    float ps[4] = {0.f, 0.f, 0.f, 0.f};
#pragma unroll
    for (int jj = 0; jj < 8; ++jj) {
        int j = ty * 8 + jj;
        float e0 = __expf(acc[0][jj] - m[0]);
        float e1 = __expf(acc[1][jj] - m[1]);
        float e2 = __expf(acc[2][jj] - m[2]);
        float e3 = __expf(acc[3][jj] - m[3]);
        ps[0] += e0; ps[1] += e1; ps[2] += e2; ps[3] += e3;
        float4 ev; ev.x = e0; ev.y = e1; ev.z = e2; ev.w = e3;
        *(float4*)&pT[j * 68 + tx * 4] = ev;
    }
#pragma unroll
    for (int ii = 0; ii < 4; ++ii) red[(tx * 4 + ii) * 17 + ty] = ps[ii];
    __syncthreads();
    float l[4];
#pragma unroll
    for (int ii = 0; ii < 4; ++ii) {
        float s = 0.f;
        for (int t = 0; t < 16; ++t) s += red[(tx * 4 + ii) * 17 + t];
        l[ii] = s;
    }

    if (ty == 0) {
#pragma unroll
        for (int ii = 0; ii < 4; ++ii) {
            int i = tx * 4 + ii;
            lse4[((size_t)bh * 4 + r) * 4096 + posl[i]] = m[ii] + __logf(l[ii]);
        }
    }

    // PV: rows i=tx*4..+4, cols c=ty*4..+4, K=128. V via uniform base +
    // 32-bit offsets.
    const char* vb8 = (const char*)v + ((size_t)bh << 20);   // uniform
    int coff = ty * 16;                                       // byte col offset
    float acc2[4][4];
#pragma unroll
    for (int i = 0; i < 4; ++i)
#pragma unroll
        for (int j = 0; j < 4; ++j) acc2[i][j] = 0.f;

    float4 p0 = *(const float4*)(vb8 + (voff[0] + coff));
    float4 p1 = *(const float4*)(vb8 + (voff[1] + coff));
    float4 p2 = *(const float4*)(vb8 + (voff[2] + coff));
    float4 p3 = *(const float4*)(vb8 + (voff[3] + coff));
    for (int j0 = 0; j0 < 128; j0 += 4) {
        float4 c0 = p0, c1 = p1, c2 = p2, c3 = p3;
        if (j0 + 4 < 128) {
            p0 = *(const float4*)(vb8 + (voff[j0 + 4] + coff));
            p1 = *(const float4*)(vb8 + (voff[j0 + 5] + coff));
            p2 = *(const float4*)(vb8 + (voff[j0 + 6] + coff));
            p3 = *(const float4*)(vb8 + (voff[j0 + 7] + coff));
        }
#define PVSTEP(JJ, CV)                                                       \
        {                                                                    \
            float a_[4];                                                     \
            *(float4*)a_ = *(const float4*)&pT[(j0 + (JJ)) * 68 + tx * 4];   \
            acc2[0][0] = fmaf(a_[0], CV.x, acc2[0][0]);                      \
            acc2[0][1] = fmaf(a_[0], CV.y, acc2[0][1]);                      \
            acc2[0][2] = fmaf(a_[0], CV.z, acc2[0][2]);                      \
            acc2[0][3] = fmaf(a_[0], CV.w, acc2[0][3]);                      \
            acc2[1][0] = fmaf(a_[1], CV.x, acc2[1][0]);                      \
            acc2[1][1] = fmaf(a_[1], CV.y, acc2[1][1]);                      \
            acc2[1][2] = fmaf(a_[1], CV.z, acc2[1][2]);                      \
            acc2[1][3] = fmaf(a_[1], CV.w, acc2[1][3]);                      \
            acc2[2][0] = fmaf(a_[2], CV.x, acc2[2][0]);                      \
            acc2[2][1] = fmaf(a_[2], CV.y, acc2[2][1]);                      \
            acc2[2][2] = fmaf(a_[2], CV.z, acc2[2][2]);                      \
            acc2[2][3] = fmaf(a_[2], CV.w, acc2[2][3]);                      \
            acc2[3][0] = fmaf(a_[3], CV.x, acc2[3][0]);                      \
            acc2[3][1] = fmaf(a_[3], CV.y, acc2[3][1]);                      \
            acc2[3][2] = fmaf(a_[3], CV.z, acc2[3][2]);                      \
            acc2[3][3] = fmaf(a_[3], CV.w, acc2[3][3]);                      \
        }
        PVSTEP(0, c0)
        PVSTEP(1, c1)
        PVSTEP(2, c2)
        PVSTEP(3, c3)
#undef PVSTEP
    }
#pragma unroll
    for (int ii = 0; ii < 4; ++ii) {
        int i = tx * 4 + ii;
        float rl = 1.0f / l[ii];
        size_t ob = (((size_t)bh * 4 + r) * 4096 + posl[i]) * 64 + ty * 4;
        float4 ov;
        ov.x = acc2[ii][0] * rl;
        ov.y = acc2[ii][1] * rl;
        ov.z = acc2[ii][2] * rl;
        ov.w = acc2[ii][3] * rl;
        *(float4*)&o4[ob] = ov;
    }
}

// ---------------------------------------------------------------------------
// Combine hash rounds (softmax over per-round lse). Grid 32768.
// ---------------------------------------------------------------------------
__global__ __launch_bounds__(256) void combine_kernel(const float* __restrict__ o4,
                                                      const float* __restrict__ lse4,
                                                      float* __restrict__ o_bt) {
    int tid = threadIdx.x;
    int gt = blockIdx.x * 4 + (tid >> 6);  // global token 0..131071
    int d = tid & 63;
    int bh = gt >> 12, p = gt & 4095;
    size_t base = ((size_t)bh * 4) * 4096 + p;
    float l0 = lse4[base];
    float l1 = lse4[base + 4096];
    float l2 = lse4[base + 8192];
    float l3 = lse4[base + 12288];
    float mm = fmaxf(fmaxf(l0, l1), fmaxf(l2, l3));
    float w0 = __expf(l0 - mm), w1 = __expf(l1 - mm);
    float w2 = __expf(l2 - mm), w3 = __expf(l3 - mm);
    float W = w0 + w1 + w2 + w3;
    size_t ob = (((size_t)bh * 4) * 4096 + p) * 64 + d;
    const size_t rs = (size_t)4096 * 64;
    float o = w0 * o4[ob]
            + w1 * o4[ob + rs]
            + w2 * o4[ob + 2 * rs]
            + w3 * o4[ob + 3 * rs];
    int b = bh >> 4, h = bh & 15;
    o_bt[((size_t)b * 4096 + p) * 1024 + h * 64 + d] = o / W;
}

// ---------------------------------------------------------------------------
extern "C" void kernel_launch(void* const* d_in, const int* in_sizes, int n_in,
                              void* d_out, int out_size, void* d_ws, size_t ws_size,
                              hipStream_t stream) {
    const float* x    = (const float*)d_in[0];   // queries (2,4096,1024)
    const float* Wqk  = (const float*)d_in[4];   // (1024,1024)
    const float* Wv   = (const float*)d_in[5];
    const float* Wout = (const float*)d_in[6];
    const float* bout = (const float*)d_in[7];   // (1024,)
    const float* rot  = (const float*)d_in[8];   // (64,4,32)
    float* out = (float*)d_out;

    char* ws = (char*)d_ws;
    float* qk32          = (float*)(ws);                        // 33,554,432 B (reused as o_bt)
    float* v             = (float*)(ws + 33554432);             // 33,554,432
    float* o4            = (float*)(ws + 67108864);             // 134,217,728
    float* lse4          = (float*)(ws + 201326592);            // 2,097,152
    int* keys            = (int*)(ws + 203423744);              // 2,097,152
    int* st_sorted       = (int*)(ws + 205520896);              // 2,097,152
    float* o_bt          = qk32;                                // alias: qk32 dead after attn

    proj2<<<1024, 256, 0, stream>>>(x, Wqk, Wv, qk32, v);
    bucket32<<<2048, 256, 0, stream>>>(qk32, rot, keys);
    countsort_kernel<<<128, 256, 0, stream>>>(keys, st_sorted);
    attn_kernel<<<8192, 256, 0, stream>>>(qk32, v, st_sorted, o4, lse4);
    combine_kernel<<<32768, 256, 0, stream>>>(o4, lse4, o_bt);
    sgemm_out<<<512, 256, 0, stream>>>(o_bt, Wout, out, bout);
}